// Round 10
// baseline (805.603 us; speedup 1.0000x reference)
//
#include <hip/hip_runtime.h>
#include <hip/hip_bf16.h>

#define N_NODES 40000
#define N_EDGES 640000
#define IN_CH 64
#define HID 128
#define N_LAYERS 3

typedef unsigned short u16;
typedef unsigned int u32;

typedef __attribute__((ext_vector_type(8))) __bf16 bf16x8;
typedef __attribute__((ext_vector_type(4))) float float4v;

__device__ __forceinline__ float bf2f(u16 u) {
    union { u32 i; float f; } v; v.i = ((u32)u) << 16; return v.f;
}
__device__ __forceinline__ float bflo(u32 p) {
    union { u32 i; float f; } v; v.i = p << 16; return v.f;
}
__device__ __forceinline__ float bfhi(u32 p) {
    union { u32 i; float f; } v; v.i = p & 0xffff0000u; return v.f;
}
__device__ __forceinline__ u16 f2bf(float f) {
    union { float f; u32 i; } v; v.f = f;
    u32 i = v.i;
    u32 r = (i + 0x7fffu + ((i >> 16) & 1u)) >> 16;
    return (u16)r;
}
#if __has_builtin(__builtin_amdgcn_cvt_pk_bf16_f32)
typedef __attribute__((ext_vector_type(2))) __bf16 bf16x2_t;
__device__ __forceinline__ u32 pk2bf(float a, float b) {
    bf16x2_t p = __builtin_amdgcn_cvt_pk_bf16_f32(a, b);
    union { bf16x2_t v; u32 u; } c; c.v = p; return c.u;
}
#else
__device__ __forceinline__ u32 pk2bf(float a, float b) {
    return (u32)f2bf(a) | ((u32)f2bf(b) << 16);
}
#endif
__device__ __forceinline__ float silu_f(float x) {
    float d = 1.0f + __expf(-x);
#if __has_builtin(__builtin_amdgcn_rcpf)
    return x * __builtin_amdgcn_rcpf(d);
#else
    return __fdividef(x, d);
#endif
}

// ---- LDS weight staging: 128 rows x 64-k chunk ----
#define W_STRIDE 72
// 256-thread version (node/embed kernels)
__device__ __forceinline__ void stage_w64(const u16* __restrict__ g, u16* s, int t,
                                          int chunk, int rowstride_u32) {
    const u32* gp = (const u32*)g;
    u32* sp = (u32*)s;
#pragma unroll
    for (int it = 0; it < 4; ++it) {
        int i4 = t + it * 256;
        int n = i4 >> 3, j = i4 & 7;
        *(uint4*)(sp + n * 36 + j * 4) = *(const uint4*)(gp + n * rowstride_u32 + chunk * 32 + j * 4);
    }
}
// 512-thread version (edge kernel)
__device__ __forceinline__ void stage_w64_512(const u16* __restrict__ g, u16* s, int t,
                                              int chunk, int rowstride_u32) {
    const u32* gp = (const u32*)g;
    u32* sp = (u32*)s;
#pragma unroll
    for (int it = 0; it < 2; ++it) {
        int i4 = t + it * 512;
        int n = i4 >> 3, j = i4 & 7;
        *(uint4*)(sp + n * 36 + j * 4) = *(const uint4*)(gp + n * rowstride_u32 + chunk * 32 + j * 4);
    }
}

// B-row permutation: storage row r holds canonical output channel (r&15)*8 + (r>>4),
// so MFMA lane li's 8 C-tiles land on canonical cols li*8..li*8+7 (contiguous stores).
__device__ __forceinline__ int permch(int r) { return ((r & 15) << 3) | (r >> 4); }

// ---------------- dtype detection ----------------
__global__ void detect_kernel(const void* __restrict__ w_raw,
                              const void* __restrict__ eidx_raw,
                              int* __restrict__ flags) {
    __shared__ int s_big, s_hi;
    if (threadIdx.x == 0) { s_big = 0; s_hi = 0; }
    __syncthreads();
    const u16* w16 = (const u16*)w_raw;
    for (int i = threadIdx.x; i < 8192; i += blockDim.x) {
        float v = bf2f(w16[i]);
        if (!(fabsf(v) <= 1.0f)) s_big = 1;
    }
    const u32* e32 = (const u32*)eidx_raw;
    for (int i = threadIdx.x; i < 256; i += blockDim.x) {
        if (e32[2 * i + 1] != 0u) s_hi = 1;
    }
    __syncthreads();
    if (threadIdx.x == 0) {
        flags[0] = s_big ? 0 : 1;   // 1 => floats are bf16
        flags[1] = s_hi ? 0 : 1;    // 1 => edge_index int64
    }
}

// ---------------- fused small fp32 conversions ----------------
__global__ void small_cvt_kernel(
    const void* __restrict__ embB_raw, const void* __restrict__ eB1_raw,
    const void* __restrict__ eB2_raw, const void* __restrict__ pB1_raw,
    const void* __restrict__ pB2_raw, const void* __restrict__ pW2_raw,
    const void* __restrict__ eW1_raw, const void* __restrict__ nB1_raw,
    const void* __restrict__ nB2_raw,
    float* __restrict__ dstf, const int* __restrict__ flags)
{
    int i = blockIdx.x * blockDim.x + threadIdx.x;
    if (i >= 2820) return;
    const void* src; int si;
    if (i < 128)       { src = embB_raw; si = i; }
    else if (i < 512)  { src = eB1_raw;  si = i - 128; }
    else if (i < 896)  { src = eB2_raw;  si = i - 512; }
    else if (i < 1280) { src = pB1_raw;  si = i - 896; }
    else if (i < 1284) { src = pB2_raw;  si = i - 1280; if (si >= 3) { dstf[i] = 0.f; return; } }
    else if (i < 1668) { src = pW2_raw;  si = i - 1284; }
    else if (i < 2052) { int j = i - 1668; src = eW1_raw; si = (j >> 7) * 32896 + 32768 + (j & 127); }
    else if (i < 2436) { src = nB1_raw;  si = i - 2052; }
    else               { src = nB2_raw;  si = i - 2436; }
    dstf[i] = flags[0] ? bf2f(((const u16*)src)[si]) : ((const float*)src)[si];
}

// ---------------- fused weight transpose+cvt to bf16 [n][k] ----------------
__global__ void wcvt_kernel(
    const void* __restrict__ eW1_raw, const void* __restrict__ eW2_raw,
    const void* __restrict__ pW1_raw, const void* __restrict__ nW1_raw,
    const void* __restrict__ nW2_raw, const void* __restrict__ embW_raw,
    u16* __restrict__ W1abt, u16* __restrict__ W2t, u16* __restrict__ pW1t,
    u16* __restrict__ nW1t, u16* __restrict__ nW2t, u16* __restrict__ embWt,
    const int* __restrict__ flags)
{
    int z = blockIdx.z, l = blockIdx.y;
    int i = blockIdx.x * blockDim.x + threadIdx.x;
    const void* src; u16* dst; int si, di;
    if (z == 0) {           // edge W1 [257][128] -> rows: [o<128: h_i | o>=128: h_j], permuted
        if (i >= 32768) return;
        int o = i >> 7, k = i & 127;
        int ch = permch(o & 127);
        si = l * 32896 + ((o < 128) ? (k * 128 + ch) : ((128 + k) * 128 + ch));
        src = eW1_raw; dst = W1abt; di = l * 32768 + i;
    } else if (z == 1) {    // edge W2, permuted rows
        if (i >= 16384) return;
        int n = i >> 7, k = i & 127;
        si = l * 16384 + k * 128 + permch(n); src = eW2_raw; dst = W2t; di = l * 16384 + i;
    } else if (z == 2) {    // pos W1, NOT permuted
        if (i >= 16384) return;
        int n = i >> 7, k = i & 127;
        si = l * 16384 + k * 128 + n; src = pW1_raw; dst = pW1t; di = l * 16384 + i;
    } else if (z == 3) {    // node W1, permuted rows
        if (i >= 32768) return;
        int n = i >> 8, k = i & 255;
        si = l * 32768 + k * 128 + permch(n); src = nW1_raw; dst = nW1t; di = l * 32768 + i;
    } else if (z == 4) {    // node W2, permuted rows
        if (i >= 16384) return;
        int n = i >> 7, k = i & 127;
        si = l * 16384 + k * 128 + permch(n); src = nW2_raw; dst = nW2t; di = l * 16384 + i;
    } else {                // emb W [64][128] -> [128][64], permuted rows
        if (l != 0 || i >= 8192) return;
        int n = i >> 6, k = i & 63;
        si = k * 128 + permch(n); src = embW_raw; dst = embWt; di = i;
    }
    float v = flags[0] ? bf2f(((const u16*)src)[si]) : ((const float*)src)[si];
    dst[di] = f2bf(v);
}

// ---------------- counting sort by dst (reads raw edge_index) ----------------
__global__ void cnt_kernel(const void* __restrict__ eidx, int* __restrict__ cnt,
                           const int* __restrict__ flags) {
    int e = blockIdx.x * blockDim.x + threadIdx.x;
    if (e >= N_EDGES) return;
    int dn = flags[1] ? (int)((const long long*)eidx)[N_EDGES + e]
                      : ((const int*)eidx)[N_EDGES + e];
    atomicAdd(&cnt[dn], 1);
}

__global__ __launch_bounds__(1024) void scan_kernel(const int* __restrict__ cnt,
                                                    int* __restrict__ offs) {
    __shared__ int s_part[1024];
    const int t = threadIdx.x;
    const int base = t * 40;
    int sum = 0;
    for (int j = 0; j < 40; ++j) {
        int idx = base + j;
        sum += (idx < N_NODES) ? cnt[idx] : 0;
    }
    s_part[t] = sum;
    __syncthreads();
    for (int d = 1; d < 1024; d <<= 1) {
        int v = (t >= d) ? s_part[t - d] : 0;
        __syncthreads();
        s_part[t] += v;
        __syncthreads();
    }
    int run = (t == 0) ? 0 : s_part[t - 1];
    for (int j = 0; j < 40; ++j) {
        int idx = base + j;
        if (idx < N_NODES) { offs[idx] = run; run += cnt[idx]; }
    }
    if (t == 1023) offs[N_NODES] = run;
}

__global__ void scatter_kernel(const void* __restrict__ eidx,
                               const int* __restrict__ offs, int* __restrict__ cur,
                               int* __restrict__ ssrc, int* __restrict__ sdst,
                               const int* __restrict__ flags) {
    int e = blockIdx.x * blockDim.x + threadIdx.x;
    if (e >= N_EDGES) return;
    int sn, dn;
    if (flags[1]) {
        sn = (int)((const long long*)eidx)[e];
        dn = (int)((const long long*)eidx)[N_EDGES + e];
    } else {
        sn = ((const int*)eidx)[e];
        dn = ((const int*)eidx)[N_EDGES + e];
    }
    int p = offs[dn] + atomicAdd(&cur[dn], 1);
    ssrc[p] = sn;
    sdst[p] = dn;
}

// ---------------- pos init -> f32 ----------------
__global__ void posinit_kernel(const void* __restrict__ pos_raw, float* __restrict__ posf,
                               const int* __restrict__ flags) {
    int i = blockIdx.x * blockDim.x + threadIdx.x;
    if (i < N_NODES * 3)
        posf[i] = flags[0] ? bf2f(((const u16*)pos_raw)[i]) : ((const float*)pos_raw)[i];
}

#define ACT_STRIDE 136

// ================= fused embed + uv(layer0) =================
__global__ __launch_bounds__(256, 3) void embed_uv_kernel(
    const void* __restrict__ x_raw, const u16* __restrict__ embWt, const float* __restrict__ embB,
    const u16* __restrict__ W1abt, const float* __restrict__ b1,
    u16* __restrict__ h, u16* __restrict__ uv, const int* __restrict__ flags)
{
    __shared__ __align__(16) u16 s_x[64 * 72];
    __shared__ __align__(16) u16 s_h[64 * ACT_STRIDE];
    __shared__ __align__(16) u16 s_w[128 * W_STRIDE];

    const int t = threadIdx.x;
    const int n0 = blockIdx.x * 64;
    const int wv = t >> 6, lane = t & 63, quad = lane >> 4, li = lane & 15;
    const int rowA = wv * 16 + li;
    const int rowC = wv * 16 + quad * 4;

    {   // load x rows -> bf16 LDS
        int el = t >> 2, pt4 = t & 3;
        u32* op = (u32*)s_x + el * 36 + pt4 * 8;
        if (flags[0]) {
            const u32* xp = (const u32*)x_raw + (size_t)(n0 + el) * 32 + pt4 * 8;
            *(uint4*)(op)     = *(const uint4*)(xp);
            *(uint4*)(op + 4) = *(const uint4*)(xp + 4);
        } else {
            const float* xp = (const float*)x_raw + (size_t)(n0 + el) * 64 + pt4 * 16;
#pragma unroll
            for (int j = 0; j < 8; ++j) op[j] = pk2bf(xp[2 * j], xp[2 * j + 1]);
        }
    }
    stage_w64(embWt, s_w, t, 0, 32);
    __syncthreads();

    // h = x @ embW + b  (K=64)   [permuted B: lane li -> canonical cols li*8..+7]
    float4v acc[8];
#pragma unroll
    for (int c = 0; c < 8; ++c) {
        float bias = embB[li * 8 + c];
#pragma unroll
        for (int r = 0; r < 4; ++r) acc[c][r] = bias;
    }
#pragma unroll
    for (int kk2 = 0; kk2 < 2; ++kk2) {
        const bf16x8 av = *(const bf16x8*)(s_x + rowA * 72 + kk2 * 32 + quad * 8);
#pragma unroll
        for (int c = 0; c < 8; ++c) {
            const bf16x8 bv = *(const bf16x8*)(s_w + (c * 16 + li) * W_STRIDE + kk2 * 32 + quad * 8);
            acc[c] = __builtin_amdgcn_mfma_f32_16x16x32_bf16(av, bv, acc[c], 0, 0, 0);
        }
    }
    // write h (global + LDS): contiguous uint4 per row
#pragma unroll
    for (int r = 0; r < 4; ++r) {
        u32 res[4];
#pragma unroll
        for (int c2 = 0; c2 < 4; ++c2)
            res[c2] = pk2bf(acc[2 * c2][r], acc[2 * c2 + 1][r]);
        *(uint4*)((u32*)s_h + (rowC + r) * (ACT_STRIDE / 2) + li * 4) = *(uint4*)res;
        *(uint4*)((u32*)h + (size_t)(n0 + rowC + r) * 64 + li * 4) = *(uint4*)res;
    }

    // uv = [h@W1a + b1 | h@W1b]   [permuted B per half]
    float4v a2[16];
#pragma unroll
    for (int ct = 0; ct < 16; ++ct) {
        float bias = (ct < 8) ? b1[li * 8 + ct] : 0.0f;
#pragma unroll
        for (int r = 0; r < 4; ++r) a2[ct][r] = bias;
    }
#pragma unroll
    for (int half = 0; half < 2; ++half) {
#pragma unroll
        for (int chunk = 0; chunk < 2; ++chunk) {
            __syncthreads();
            stage_w64(W1abt + half * 16384, s_w, t, chunk, 64);
            __syncthreads();
#pragma unroll
            for (int kk2 = 0; kk2 < 2; ++kk2) {
                const bf16x8 av = *(const bf16x8*)(s_h + rowA * ACT_STRIDE + chunk * 64 + kk2 * 32 + quad * 8);
#pragma unroll
                for (int c = 0; c < 8; ++c) {
                    const bf16x8 bv = *(const bf16x8*)(s_w + (c * 16 + li) * W_STRIDE + kk2 * 32 + quad * 8);
                    a2[half * 8 + c] = __builtin_amdgcn_mfma_f32_16x16x32_bf16(av, bv, a2[half * 8 + c], 0, 0, 0);
                }
            }
        }
    }
#pragma unroll
    for (int half = 0; half < 2; ++half) {
#pragma unroll
        for (int r = 0; r < 4; ++r) {
            u32 res[4];
#pragma unroll
            for (int c2 = 0; c2 < 4; ++c2)
                res[c2] = pk2bf(a2[half * 8 + 2 * c2][r], a2[half * 8 + 2 * c2 + 1][r]);
            *(uint4*)((u32*)uv + (size_t)(n0 + rowC + r) * 128 + half * 64 + li * 4) = *(uint4*)res;
        }
    }
}

// ================= edge kernel: 128 edges / 512 threads (8 waves) =================
#define TILE_E 128

__global__ __launch_bounds__(512, 2) void edge_mfma_kernel(
    const int* __restrict__ ssrc, const int* __restrict__ sdst,
    const u16* __restrict__ uv, const float* __restrict__ posf,
    const float* __restrict__ w1c_g,
    const u16* __restrict__ W2t, const float* __restrict__ b2,
    const u16* __restrict__ pW1t, const float* __restrict__ pb1,
    const float* __restrict__ pW2, const float* __restrict__ pb2,
    float* __restrict__ agg, float* __restrict__ pd)
{
    __shared__ __align__(16) u16 s_act[TILE_E * ACT_STRIDE];   // 34.8 KB
    __shared__ __align__(16) u16 s_w[128 * W_STRIDE];          // 18.4 KB
    __shared__ float s_w1c[128];
    __shared__ float s_d2[TILE_E];
    __shared__ float s_rel[TILE_E * 3];
    __shared__ int s_dstn[TILE_E];

    const int t = threadIdx.x;
    const int e0 = blockIdx.x * TILE_E;
    const int wv = t >> 6, lane = t & 63, quad = lane >> 4, li = lane & 15;
    const int rowA = wv * 16 + li;
    const int rowC = wv * 16 + quad * 4;

    // ---- gather + meta ----
    {
        const int el = t >> 2, pt4 = t & 3;
        int eg = e0 + el;
        int dNg = sdst[eg], sNg = ssrc[eg];
        const uint4* up = (const uint4*)((const u32*)uv + (size_t)dNg * 128 + pt4 * 16);
        const uint4* vp = (const uint4*)((const u32*)uv + (size_t)sNg * 128 + 64 + pt4 * 16);
        uint4 uu[4], vv[4];
#pragma unroll
        for (int q4 = 0; q4 < 4; ++q4) { uu[q4] = up[q4]; vv[q4] = vp[q4]; }

        if (t < TILE_E) {
            int e = e0 + t;
            int sN = ssrc[e], dN = sdst[e];
            s_dstn[t] = dN;
            float r0 = posf[dN * 3 + 0] - posf[sN * 3 + 0];
            float r1 = posf[dN * 3 + 1] - posf[sN * 3 + 1];
            float r2 = posf[dN * 3 + 2] - posf[sN * 3 + 2];
            s_rel[t * 3 + 0] = r0; s_rel[t * 3 + 1] = r1; s_rel[t * 3 + 2] = r2;
            s_d2[t] = r0 * r0 + r1 * r1 + r2 * r2;
        }
        if (t < 128) s_w1c[t] = w1c_g[t];
        stage_w64_512(W2t, s_w, t, 0, 64);
        __syncthreads();

        // ---- t1 = silu(u[dst] + v[src] + d2*w1c) ----
        float d2 = s_d2[el];
        u32* outp = (u32*)s_act + el * (ACT_STRIDE / 2) + pt4 * 16;
        const float* wc = s_w1c + pt4 * 32;
#pragma unroll
        for (int q4 = 0; q4 < 4; ++q4) {
            u32 res[4];
#pragma unroll
            for (int j = 0; j < 4; ++j) {
                u32 ua = ((const u32*)&uu[q4])[j], va = ((const u32*)&vv[q4])[j];
                int col = q4 * 8 + j * 2;
                float x0 = fmaf(d2, wc[col],     bflo(ua) + bflo(va));
                float x1 = fmaf(d2, wc[col + 1], bfhi(ua) + bfhi(va));
                res[j] = pk2bf(silu_f(x0), silu_f(x1));
            }
            *(uint4*)(outp + q4 * 4) = *(uint4*)res;
        }
    }
    __syncthreads();

    // m_pre = t1 @ W2 + b2   [permuted B: lane li -> canonical cols li*8..+7]
    float4v acc[8];
#pragma unroll
    for (int c = 0; c < 8; ++c) {
        float bias = b2[li * 8 + c];
#pragma unroll
        for (int r = 0; r < 4; ++r) acc[c][r] = bias;
    }
#pragma unroll
    for (int p = 0; p < 2; ++p) {
        if (p) {
            __syncthreads();
            stage_w64_512(W2t, s_w, t, 1, 64);
            __syncthreads();
        }
#pragma unroll
        for (int kk2 = 0; kk2 < 2; ++kk2) {
            const bf16x8 av = *(const bf16x8*)(s_act + rowA * ACT_STRIDE + p * 64 + kk2 * 32 + quad * 8);
#pragma unroll
            for (int c = 0; c < 8; ++c) {
                const bf16x8 bv = *(const bf16x8*)(s_w + (c * 16 + li) * W_STRIDE + kk2 * 32 + quad * 8);
                acc[c] = __builtin_amdgcn_mfma_f32_16x16x32_bf16(av, bv, acc[c], 0, 0, 0);
            }
        }
    }
    __syncthreads();

    // m -> s_act: canonical order, contiguous ds_write_b128 per row
#pragma unroll
    for (int r = 0; r < 4; ++r) {
        u32 res[4];
#pragma unroll
        for (int c2 = 0; c2 < 4; ++c2)
            res[c2] = pk2bf(silu_f(acc[2 * c2][r]), silu_f(acc[2 * c2 + 1][r]));
        *(uint4*)((u32*)s_act + (rowC + r) * (ACT_STRIDE / 2) + li * 4) = *(uint4*)res;
    }
    stage_w64_512(pW1t, s_w, t, 0, 64);
    __syncthreads();

    // agg segmented reduction: 8 groups of 16 rows x 64 col-pairs
    {
        int c32 = t & 63, grp = t >> 6;
        int r0 = grp * 16;
        float run0 = 0.f, run1 = 0.f;
        int cur = s_dstn[r0];
        for (int r = r0; r < r0 + 16; ++r) {
            int dn = s_dstn[r];
            if (dn != cur) {
                atomicAdd(&agg[(size_t)cur * HID + 2 * c32], run0);
                atomicAdd(&agg[(size_t)cur * HID + 2 * c32 + 1], run1);
                run0 = run1 = 0.f; cur = dn;
            }
            u32 mm = *((const u32*)s_act + r * (ACT_STRIDE / 2) + c32);
            run0 += bflo(mm);
            run1 += bfhi(mm);
        }
        atomicAdd(&agg[(size_t)cur * HID + 2 * c32], run0);
        atomicAdd(&agg[(size_t)cur * HID + 2 * c32 + 1], run1);
    }

    // pos MLP (pW1t NOT permuted: cols stay c*16+li, output dot-reduced only)
#pragma unroll
    for (int c = 0; c < 8; ++c) {
        float bias = pb1[c * 16 + li];
#pragma unroll
        for (int r = 0; r < 4; ++r) acc[c][r] = bias;
    }
#pragma unroll
    for (int p = 0; p < 2; ++p) {
        if (p) {
            __syncthreads();
            stage_w64_512(pW1t, s_w, t, 1, 64);
            __syncthreads();
        }
#pragma unroll
        for (int kk2 = 0; kk2 < 2; ++kk2) {
            const bf16x8 av = *(const bf16x8*)(s_act + rowA * ACT_STRIDE + p * 64 + kk2 * 32 + quad * 8);
#pragma unroll
            for (int c = 0; c < 8; ++c) {
                const bf16x8 bv = *(const bf16x8*)(s_w + (c * 16 + li) * W_STRIDE + kk2 * 32 + quad * 8);
                acc[c] = __builtin_amdgcn_mfma_f32_16x16x32_bf16(av, bv, acc[c], 0, 0, 0);
            }
        }
    }
    float part[4] = {0.f, 0.f, 0.f, 0.f};
#pragma unroll
    for (int c = 0; c < 8; ++c) {
        float pw = pW2[c * 16 + li];
#pragma unroll
        for (int r = 0; r < 4; ++r) part[r] += silu_f(acc[c][r]) * pw;
    }
#pragma unroll
    for (int r = 0; r < 4; ++r) {
        part[r] += __shfl_xor(part[r], 1, 64);
        part[r] += __shfl_xor(part[r], 2, 64);
        part[r] += __shfl_xor(part[r], 4, 64);
        part[r] += __shfl_xor(part[r], 8, 64);
    }
    __syncthreads();
    if (li == 0) {
        float pb2v = pb2[0];
#pragma unroll
        for (int r = 0; r < 4; ++r) s_d2[rowC + r] = part[r] + pb2v;
    }
    __syncthreads();
    if (t < 24) {   // 3 axes x 8 row-groups
        int a = t % 3, grp = t / 3;
        int r0 = grp * 16;
        float run = 0.f;
        int cur = s_dstn[r0];
        for (int r = r0; r < r0 + 16; ++r) {
            int dn = s_dstn[r];
            if (dn != cur) {
                atomicAdd(&pd[(size_t)cur * 3 + a], run);
                run = 0.f; cur = dn;
            }
            run += s_rel[r * 3 + a] * s_d2[r];
        }
        atomicAdd(&pd[(size_t)cur * 3 + a], run);
    }
}

// ================= fused node MLP + uv(next layer) + output =================
#define A_STRIDE 264

__global__ __launch_bounds__(256, 3) void node_uv_kernel(
    const u16* __restrict__ h_in, float* __restrict__ agg,
    const u16* __restrict__ W1t, const float* __restrict__ b1,
    const u16* __restrict__ W2t, const float* __restrict__ b2,
    const u16* __restrict__ W1abt_nx, const float* __restrict__ b1_nx,
    u16* __restrict__ h_out, u16* __restrict__ uv,
    float* __restrict__ posf, float* __restrict__ pd, const int* __restrict__ cnt,
    void* __restrict__ outp, const int* __restrict__ flags, int do_out)
{
    __shared__ __align__(16) u16 s_a[64 * A_STRIDE];
    __shared__ __align__(16) u16 s_w[128 * W_STRIDE];

    const int t = threadIdx.x;
    const int n0 = blockIdx.x * 64;
    const int wv = t >> 6, lane = t & 63, quad = lane >> 4, li = lane & 15;
    const int rowA = wv * 16 + li;
    const int rowC = wv * 16 + quad * 4;

    {   // A = [h | bf16(agg)]; zero agg after read
        int nl = t >> 2, pt4 = t & 3;
        const uint4* hp = (const uint4*)((const u32*)h_in + (size_t)(n0 + nl) * 64 + pt4 * 16);
        u32* rowp = (u32*)s_a + nl * (A_STRIDE / 2) + pt4 * 16;
#pragma unroll
        for (int j = 0; j < 4; ++j) *(uint4*)(rowp + j * 4) = hp[j];
        float* ap = agg + (size_t)(n0 + nl) * HID + pt4 * 32;
        rowp += 64;
#pragma unroll
        for (int j = 0; j < 16; ++j) {
            float2 v = *(const float2*)(ap + j * 2);
            rowp[j] = pk2bf(v.x, v.y);
        }
        float4 z = {0.f, 0.f, 0.f, 0.f};
#pragma unroll
        for (int j = 0; j < 8; ++j) *(float4*)(ap + j * 4) = z;
    }
    stage_w64(W1t, s_w, t, 0, 128);
    __syncthreads();

    float4v acc[8];
#pragma unroll
    for (int c = 0; c < 8; ++c) {
        float bias = b1[li * 8 + c];
#pragma unroll
        for (int r = 0; r < 4; ++r) acc[c][r] = bias;
    }
#pragma unroll
    for (int p = 0; p < 4; ++p) {
        if (p) {
            __syncthreads();
            stage_w64(W1t, s_w, t, p, 128);
            __syncthreads();
        }
#pragma unroll
        for (int kk2 = 0; kk2 < 2; ++kk2) {
            const bf16x8 av = *(const bf16x8*)(s_a + rowA * A_STRIDE + p * 64 + kk2 * 32 + quad * 8);
#pragma unroll
            for (int c = 0; c < 8; ++c) {
                const bf16x8 bv = *(const bf16x8*)(s_w + (c * 16 + li) * W_STRIDE + kk2 * 32 + quad * 8);
                acc[c] = __builtin_amdgcn_mfma_f32_16x16x32_bf16(av, bv, acc[c], 0, 0, 0);
            }
        }
    }

    __syncthreads();
    u16* s_t1 = s_a;   // overlay; t1 canonical via permuted nW1t
#pragma unroll
    for (int r = 0; r < 4; ++r) {
        u32 res[4];
#pragma unroll
        for (int c2 = 0; c2 < 4; ++c2)
            res[c2] = pk2bf(silu_f(acc[2 * c2][r]), silu_f(acc[2 * c2 + 1][r]));
        *(uint4*)((u32*)s_t1 + (rowC + r) * (ACT_STRIDE / 2) + li * 4) = *(uint4*)res;
    }
    stage_w64(W2t, s_w, t, 0, 64);
    __syncthreads();

#pragma unroll
    for (int c = 0; c < 8; ++c) {
        float bias = b2[li * 8 + c];
#pragma unroll
        for (int r = 0; r < 4; ++r) acc[c][r] = bias;
    }
#pragma unroll
    for (int p = 0; p < 2; ++p) {
        if (p) {
            __syncthreads();
            stage_w64(W2t, s_w, t, 1, 64);
            __syncthreads();
        }
#pragma unroll
        for (int kk2 = 0; kk2 < 2; ++kk2) {
            const bf16x8 av = *(const bf16x8*)(s_t1 + rowA * ACT_STRIDE + p * 64 + kk2 * 32 + quad * 8);
#pragma unroll
            for (int c = 0; c < 8; ++c) {
                const bf16x8 bv = *(const bf16x8*)(s_w + (c * 16 + li) * W_STRIDE + kk2 * 32 + quad * 8);
                acc[c] = __builtin_amdgcn_mfma_f32_16x16x32_bf16(av, bv, acc[c], 0, 0, 0);
            }
        }
    }

    // epilogue: h (canonical cols li*8..+7 per lane)
    if (do_out) {
        if (flags[0]) {
#pragma unroll
            for (int r = 0; r < 4; ++r) {
                u32 res[4];
#pragma unroll
                for (int c2 = 0; c2 < 4; ++c2)
                    res[c2] = pk2bf(acc[2 * c2][r], acc[2 * c2 + 1][r]);
                *(uint4*)((u32*)outp + (size_t)(n0 + rowC + r) * 64 + li * 4) = *(uint4*)res;
            }
        } else {
#pragma unroll
            for (int r = 0; r < 4; ++r) {
                float* op = (float*)outp + (size_t)(n0 + rowC + r) * HID + li * 8;
                float4 lo = {acc[0][r], acc[1][r], acc[2][r], acc[3][r]};
                float4 hi = {acc[4][r], acc[5][r], acc[6][r], acc[7][r]};
                *(float4*)op = lo;
                *(float4*)(op + 4) = hi;
            }
        }
    } else {
#pragma unroll
        for (int r = 0; r < 4; ++r) {
            u32 res[4];
#pragma unroll
            for (int c2 = 0; c2 < 4; ++c2)
                res[c2] = pk2bf(acc[2 * c2][r], acc[2 * c2 + 1][r]);
            *(uint4*)((u32*)s_t1 + (rowC + r) * (ACT_STRIDE / 2) + li * 4) = *(uint4*)res;
            *(uint4*)((u32*)h_out + (size_t)(n0 + rowC + r) * 64 + li * 4) = *(uint4*)res;
        }
    }

    // pos update + pd zero (+ pos out)
    if (t < 192) {
        int nl = t / 3, a = t % 3;
        int n = n0 + nl;
        float dg = (float)cnt[n];
        dg = dg < 1.0f ? 1.0f : dg;
        float np = posf[n * 3 + a] + pd[n * 3 + a] / dg;
        posf[n * 3 + a] = np;
        pd[n * 3 + a] = 0.f;
        if (do_out) {
            if (flags[0]) ((u16*)outp)[(size_t)N_NODES * HID + n * 3 + a] = f2bf(np);
            else          ((float*)outp)[(size_t)N_NODES * HID + n * 3 + a] = np;
        }
    }

    if (do_out) return;

    // uv for next layer (reads s_t1 = new h, written above canonical)
    float4v a2[16];
#pragma unroll
    for (int ct = 0; ct < 16; ++ct) {
        float bias = (ct < 8) ? b1_nx[li * 8 + ct] : 0.0f;
#pragma unroll
        for (int r = 0; r < 4; ++r) a2[ct][r] = bias;
    }
#pragma unroll
    for (int half = 0; half < 2; ++half) {
#pragma unroll
        for (int chunk = 0; chunk < 2; ++chunk) {
            __syncthreads();
            stage_w64(W1abt_nx + half * 16384, s_w, t, chunk, 64);
            __syncthreads();
#pragma unroll
            for (int kk2 = 0; kk2 < 2; ++kk2) {
                const bf16x8 av = *(const bf16x8*)(s_t1 + rowA * ACT_STRIDE + chunk * 64 + kk2 * 32 + quad * 8);
#pragma unroll
                for (int c = 0; c < 8; ++c) {
                    const bf16x8 bv = *(const bf16x8*)(s_w + (c * 16 + li) * W_STRIDE + kk2 * 32 + quad * 8);
                    a2[half * 8 + c] = __builtin_amdgcn_mfma_f32_16x16x32_bf16(av, bv, a2[half * 8 + c], 0, 0, 0);
                }
            }
        }
    }
#pragma unroll
    for (int half = 0; half < 2; ++half) {
#pragma unroll
        for (int r = 0; r < 4; ++r) {
            u32 res[4];
#pragma unroll
            for (int c2 = 0; c2 < 4; ++c2)
                res[c2] = pk2bf(a2[half * 8 + 2 * c2][r], a2[half * 8 + 2 * c2 + 1][r]);
            *(uint4*)((u32*)uv + (size_t)(n0 + rowC + r) * 128 + half * 64 + li * 4) = *(uint4*)res;
        }
    }
}

extern "C" void kernel_launch(void* const* d_in, const int* in_sizes, int n_in,
                              void* d_out, int out_size, void* d_ws, size_t ws_size,
                              hipStream_t stream) {
    (void)in_sizes; (void)n_in; (void)out_size; (void)ws_size;

    const void* eidx_raw = d_in[0];
    const void* x_raw    = d_in[1];
    const void* pos_raw  = d_in[2];
    const void* embW_raw = d_in[3];
    const void* embB_raw = d_in[4];
    const void* eW1_raw  = d_in[5];
    const void* eB1_raw  = d_in[6];
    const void* eW2_raw  = d_in[7];
    const void* eB2_raw  = d_in[8];
    const void* nW1_raw  = d_in[9];
    const void* nB1_raw  = d_in[10];
    const void* nW2_raw  = d_in[11];
    const void* nB2_raw  = d_in[12];
    const void* pW1_raw  = d_in[13];
    const void* pB1_raw  = d_in[14];
    const void* pW2_raw  = d_in[15];
    const void* pB2_raw  = d_in[16];

    float* ws   = (float*)d_ws;
    float* posf = ws;                            //   120,000
    float* agg  = posf + (size_t)N_NODES * 3;    // 5,120,000
    float* pd   = agg + (size_t)N_NODES * HID;   //   120,000 (contiguous w/ agg)
    float* smallf = pd + (size_t)N_NODES * 3;    //     2,820
    float* embB = smallf;                        // [0,128)
    float* eB1f = smallf + 128;                  // [128,512)
    float* eB2f = smallf + 512;
    float* pB1f = smallf + 896;
    float* pB2f = smallf + 1280;
    float* pW2f = smallf + 1284;
    float* W1r  = smallf + 1668;
    float* nB1f = smallf + 2052;
    float* nB2f = smallf + 2436;

    u16* W1abt = (u16*)(smallf + 2820);          // 98,304
    u16* W2t   = W1abt + 3 * 256 * 128;          // 49,152
    u16* pW1t  = W2t + 3 * 128 * 128;            // 49,152
    u16* nW1t  = pW1t + 3 * 128 * 128;           // 98,304
    u16* nW2t  = nW1t + 3 * 128 * 256;           // 49,152
    u16* embWt = nW2t + 3 * 128 * 128;           //  8,192
    u16* h0    = embWt + 8192;                   // 5,120,000
    u16* h1    = h0 + (size_t)N_NODES * HID;     // 5,120,000
    u16* uvb   = h1 + (size_t)N_NODES * HID;     // 10,240,000
    int* ssrc  = (int*)(uvb + (size_t)N_NODES * 256);
    int* sdst  = ssrc + N_EDGES;
    int* cnt   = sdst + N_EDGES;                 // 40,000
    int* cur   = cnt + N_NODES;                  // 40,000 (contiguous for memset)
    int* offs  = cur + N_NODES;                  // 40,001
    int* flags = offs + N_NODES + 3;
    // total ws ≈ 68.7 MB

    detect_kernel<<<1, 256, 0, stream>>>(embW_raw, eidx_raw, flags);
    small_cvt_kernel<<<12, 256, 0, stream>>>(embB_raw, eB1_raw, eB2_raw, pB1_raw, pB2_raw,
                                             pW2_raw, eW1_raw, nB1_raw, nB2_raw, smallf, flags);
    wcvt_kernel<<<dim3(128, 3, 6), 256, 0, stream>>>(
        eW1_raw, eW2_raw, pW1_raw, nW1_raw, nW2_raw, embW_raw,
        W1abt, W2t, pW1t, nW1t, nW2t, embWt, flags);

    hipMemsetAsync(cnt, 0, 2 * (size_t)N_NODES * sizeof(int), stream);
    cnt_kernel<<<(N_EDGES + 255) / 256, 256, 0, stream>>>(eidx_raw, cnt, flags);
    scan_kernel<<<1, 1024, 0, stream>>>(cnt, offs);
    scatter_kernel<<<(N_EDGES + 255) / 256, 256, 0, stream>>>(eidx_raw, offs, cur, ssrc, sdst, flags);

    posinit_kernel<<<(N_NODES * 3 + 255) / 256, 256, 0, stream>>>(pos_raw, posf, flags);
    hipMemsetAsync(agg, 0, ((size_t)N_NODES * HID + (size_t)N_NODES * 3) * sizeof(float), stream);

    embed_uv_kernel<<<N_NODES / 64, 256, 0, stream>>>(x_raw, embWt, embB, W1abt, eB1f, h0, uvb, flags);

    u16* hin = h0;
    u16* hout = h1;
    for (int l = 0; l < N_LAYERS; ++l) {
        int last = (l == N_LAYERS - 1);
        edge_mfma_kernel<<<N_EDGES / TILE_E, 512, 0, stream>>>(
            ssrc, sdst, uvb, posf,
            W1r + l * HID,
            W2t + (size_t)l * 128 * 128, eB2f + l * HID,
            pW1t + (size_t)l * 128 * 128, pB1f + l * HID,
            pW2f + l * HID, pB2f + l,
            agg, pd);
        node_uv_kernel<<<N_NODES / 64, 256, 0, stream>>>(
            hin, agg,
            nW1t + (size_t)l * 128 * 256, nB1f + l * HID,
            nW2t + (size_t)l * 128 * 128, nB2f + l * HID,
            W1abt + (size_t)(last ? 0 : (l + 1)) * 32768, eB1f + (last ? 0 : (l + 1)) * HID,
            hout, uvb,
            posf, pd, cnt,
            d_out, flags, last ? 1 : 0);
        u16* tmp = hin; hin = hout; hout = tmp;
    }
}